// Round 1
// baseline (348.891 us; speedup 1.0000x reference)
//
#include <hip/hip_runtime.h>

#define B_ 2
#define S_ 2048
#define E_ 1024
#define H_ 16
#define D_ 64
#define M_ (B_*S_)   // 4096

typedef __attribute__((ext_vector_type(8))) short bf16x8;   // 8 bf16 in 4 VGPRs
typedef __attribute__((ext_vector_type(4))) float f32x4;
typedef __attribute__((ext_vector_type(8))) unsigned short u16x8;
typedef __attribute__((ext_vector_type(4))) unsigned short u16x4;

__device__ __forceinline__ unsigned short f2bf(float f) {
  union { float f; unsigned u; } a; a.f = f;
  unsigned u = a.u;
  return (unsigned short)((u + 0x7FFFu + ((u >> 16) & 1u)) >> 16);  // RNE
}

__device__ __forceinline__ void gload_lds16(const void* g, void* l) {
  __builtin_amdgcn_global_load_lds(
      (const __attribute__((address_space(1))) void*)g,
      (__attribute__((address_space(3))) void*)l, 16, 0, 0);
}

// ---------------- fp32 -> bf16 convert (with scale fold) ----------------
__global__ __launch_bounds__(256) void cvt_bf16(const float* __restrict__ src,
                                                unsigned short* __restrict__ dst,
                                                int n4, float scale) {
  int i = blockIdx.x * blockDim.x + threadIdx.x;
  if (i < n4) {
    float4 v = ((const float4*)src)[i];
    u16x4 o;
    o[0] = f2bf(v.x * scale);
    o[1] = f2bf(v.y * scale);
    o[2] = f2bf(v.z * scale);
    o[3] = f2bf(v.w * scale);
    ((u16x4*)dst)[i] = o;
  }
}

// ---------------- GEMM: C[m,n] = sum_k A[m,k] * W[n,k]  (y = x @ W^T) ----
// 128x128 tile, BK=32, 256 threads = 4 waves (2x2), each wave 64x64.
template<int OUT_BF16>
__global__ __launch_bounds__(256) void gemm_bt(const unsigned short* __restrict__ A,
                                               const unsigned short* __restrict__ W,
                                               void* __restrict__ Cv,
                                               int M, int N, int K) {
  __shared__ unsigned short As[128 * 32];
  __shared__ unsigned short Bs[128 * 32];
  const int tid = threadIdx.x;
  const int lane = tid & 63, wave = tid >> 6;
  const int wr = wave >> 1, wc = wave & 1;
  const int lq = lane & 15, lg = lane >> 4;
  const int row0 = blockIdx.x * 128, col0 = blockIdx.y * 128;
  f32x4 acc[4][4] = {};

  for (int kt = 0; kt < K; kt += 32) {
#pragma unroll
    for (int i = 0; i < 2; ++i) {
      int t = tid + i * 256;
      int rr = t >> 2, cc = (t & 3) * 8;
      gload_lds16(A + (size_t)(row0 + rr) * K + kt + cc, &As[t * 8]);
      gload_lds16(W + (size_t)(col0 + rr) * K + kt + cc, &Bs[t * 8]);
    }
    __syncthreads();
    bf16x8 af[4], bfr[4];
#pragma unroll
    for (int mi = 0; mi < 4; ++mi)
      af[mi] = *(const bf16x8*)&As[(wr * 64 + mi * 16 + lq) * 32 + lg * 8];
#pragma unroll
    for (int ni = 0; ni < 4; ++ni)
      bfr[ni] = *(const bf16x8*)&Bs[(wc * 64 + ni * 16 + lq) * 32 + lg * 8];
#pragma unroll
    for (int mi = 0; mi < 4; ++mi)
#pragma unroll
      for (int ni = 0; ni < 4; ++ni)
        acc[mi][ni] = __builtin_amdgcn_mfma_f32_16x16x32_bf16(af[mi], bfr[ni], acc[mi][ni], 0, 0, 0);
    __syncthreads();
  }

#pragma unroll
  for (int mi = 0; mi < 4; ++mi)
#pragma unroll
    for (int ni = 0; ni < 4; ++ni) {
      int row = row0 + wr * 64 + mi * 16 + lg * 4;
      int col = col0 + wc * 64 + ni * 16 + lq;
#pragma unroll
      for (int r = 0; r < 4; ++r) {
        float v = acc[mi][ni][r];
        if (OUT_BF16) ((unsigned short*)Cv)[(size_t)(row + r) * N + col] = f2bf(v);
        else          ((float*)Cv)[(size_t)(row + r) * N + col] = v;
      }
    }
}

// ---------------- V [B,S,E](bf16) -> VT [B*H*D, S](bf16) -----------------
__global__ __launch_bounds__(256) void transpose_v(const unsigned short* __restrict__ V,
                                                   unsigned short* __restrict__ VT) {
  __shared__ unsigned short tile[64][72];
  const int tid = threadIdx.x;
  const int s0 = blockIdx.x * 64;
  const int h = blockIdx.y;
  const int b = blockIdx.z;
  const int r = tid >> 3;
  const int c = (tid & 7) * 8;
  const unsigned short* src = V + ((size_t)(b * S_) + s0) * E_ + h * 64;
#pragma unroll
  for (int i = 0; i < 2; ++i) {
    int rr = r + i * 32;
    u16x8 v = *(const u16x8*)(src + (size_t)rr * E_ + c);
#pragma unroll
    for (int j = 0; j < 8; ++j) tile[rr][c + j] = v[j];
  }
  __syncthreads();
  unsigned short* dst = VT + ((size_t)((b * H_ + h) * 64)) * S_ + s0;
#pragma unroll
  for (int i = 0; i < 2; ++i) {
    int d = r + i * 32;
    u16x8 o;
#pragma unroll
    for (int j = 0; j < 8; ++j) o[j] = tile[c + j][d];
    *(u16x8*)(dst + (size_t)d * S_ + c) = o;
  }
}

// ---------------- flash attention ---------------------------------------
// grid: (S/64, B*H). 256 threads = 4 waves; wave w owns q rows [w*16, w*16+16).
// Score scale 1/8 is folded into W_q. Swapped QK^T: S^T = mfma(K, Q).
__global__ __launch_bounds__(256) void attn(const unsigned short* __restrict__ Q,
                                            const unsigned short* __restrict__ K,
                                            const unsigned short* __restrict__ VT,
                                            unsigned short* __restrict__ ctx) {
  __shared__ unsigned short Ks[64 * 64];       // [key][d]
  __shared__ unsigned short Vs[64 * 64];       // [dv][key]
  __shared__ unsigned short Ps[4][16 * 64];    // per wave: [q][key]
  const int tid = threadIdx.x, lane = tid & 63, wave = tid >> 6;
  const int lq = lane & 15, lg = lane >> 4;
  const int bh = blockIdx.y, b = bh >> 4, h = bh & 15;
  const int q0 = blockIdx.x * 64;

  const unsigned short* Qbase = Q + ((size_t)(b * S_) + q0 + wave * 16 + lq) * E_ + h * 64;
  bf16x8 qf0 = *(const bf16x8*)(Qbase + lg * 8);
  bf16x8 qf1 = *(const bf16x8*)(Qbase + 32 + lg * 8);
  const unsigned short* Kbase = K + (size_t)(b * S_) * E_ + h * 64;
  const unsigned short* Vtb = VT + (size_t)((b * H_ + h) * 64) * S_;

  f32x4 oacc[4] = {};
  float m_run = -1e30f, l_run = 0.f;

  for (int kc = 0; kc < S_; kc += 64) {
    __syncthreads();
#pragma unroll
    for (int i = 0; i < 2; ++i) {
      int tt = tid + i * 256;
      int r = tt >> 3, c = (tt & 7) * 8;
      gload_lds16(Kbase + (size_t)(kc + r) * E_ + c, &Ks[tt * 8]);
      gload_lds16(Vtb + (size_t)r * S_ + kc + c, &Vs[tt * 8]);
    }
    __syncthreads();

    // S^T[key][q] for 64 keys
    f32x4 st[4] = {};
#pragma unroll
    for (int mf = 0; mf < 4; ++mf) {
      bf16x8 kf0 = *(const bf16x8*)&Ks[(mf * 16 + lq) * 64 + lg * 8];
      bf16x8 kf1 = *(const bf16x8*)&Ks[(mf * 16 + lq) * 64 + 32 + lg * 8];
      st[mf] = __builtin_amdgcn_mfma_f32_16x16x32_bf16(kf0, qf0, st[mf], 0, 0, 0);
      st[mf] = __builtin_amdgcn_mfma_f32_16x16x32_bf16(kf1, qf1, st[mf], 0, 0, 0);
    }

    // online softmax for q = lq (4 redundant lanes per q)
    float cm = -1e30f;
#pragma unroll
    for (int mf = 0; mf < 4; ++mf)
#pragma unroll
      for (int r = 0; r < 4; ++r) cm = fmaxf(cm, st[mf][r]);
    cm = fmaxf(cm, __shfl_xor(cm, 16));
    cm = fmaxf(cm, __shfl_xor(cm, 32));
    float m_new = fmaxf(m_run, cm);
    float alpha = __expf(m_run - m_new);
    float ls = 0.f;
#pragma unroll
    for (int mf = 0; mf < 4; ++mf) {
      u16x4 pb;
#pragma unroll
      for (int r = 0; r < 4; ++r) {
        float p = __expf(st[mf][r] - m_new);
        ls += p;
        pb[r] = f2bf(p);
      }
      *(u16x4*)&Ps[wave][lq * 64 + mf * 16 + lg * 4] = pb;  // P[q][key]
    }
    ls += __shfl_xor(ls, 16);
    ls += __shfl_xor(ls, 32);
    l_run = l_run * alpha + ls;
    m_run = m_new;
    asm volatile("s_waitcnt lgkmcnt(0)" ::: "memory");

    // rescale O (q = lg*4 + r in PV layout)
#pragma unroll
    for (int r = 0; r < 4; ++r) {
      float ar = __shfl(alpha, lg * 4 + r);
#pragma unroll
      for (int nf = 0; nf < 4; ++nf) oacc[nf][r] *= ar;
    }

    // O[q][dv] += P @ V
#pragma unroll
    for (int ks = 0; ks < 2; ++ks) {
      bf16x8 pf = *(const bf16x8*)&Ps[wave][lq * 64 + ks * 32 + lg * 8];
#pragma unroll
      for (int nf = 0; nf < 4; ++nf) {
        bf16x8 vf = *(const bf16x8*)&Vs[(nf * 16 + lq) * 64 + ks * 32 + lg * 8];
        oacc[nf] = __builtin_amdgcn_mfma_f32_16x16x32_bf16(pf, vf, oacc[nf], 0, 0, 0);
      }
    }
  }

  // normalize + store ctx (bf16, [B,S,E] layout)
#pragma unroll
  for (int r = 0; r < 4; ++r) {
    float lr = __shfl(l_run, lg * 4 + r);
    float inv = 1.f / lr;
#pragma unroll
    for (int nf = 0; nf < 4; ++nf) {
      ctx[((size_t)(b * S_) + q0 + wave * 16 + lg * 4 + r) * E_ + h * 64 + nf * 16 + lq] =
          f2bf(oacc[nf][r] * inv);
    }
  }
}

// ---------------- launch -------------------------------------------------
extern "C" void kernel_launch(void* const* d_in, const int* in_sizes, int n_in,
                              void* d_out, int out_size, void* d_ws, size_t ws_size,
                              hipStream_t stream) {
  const float* h  = (const float*)d_in[0];
  const float* Wq = (const float*)d_in[1];
  const float* Wk = (const float*)d_in[2];
  const float* Wv = (const float*)d_in[3];
  const float* Wo = (const float*)d_in[4];
  float* out = (float*)d_out;
  char* ws = (char*)d_ws;

  const size_t SZ_H = (size_t)M_ * E_ * 2;   // 8 MiB
  const size_t SZ_W = (size_t)E_ * E_ * 2;   // 2 MiB
  unsigned short* hb  = (unsigned short*)(ws);
  unsigned short* wqb = (unsigned short*)(ws + SZ_H);
  unsigned short* wkb = (unsigned short*)(ws + SZ_H + SZ_W);
  unsigned short* wvb = (unsigned short*)(ws + SZ_H + 2 * SZ_W);
  unsigned short* wob = (unsigned short*)(ws + SZ_H + 3 * SZ_W);
  unsigned short* Qb  = (unsigned short*)(ws + SZ_H + 4 * SZ_W);
  unsigned short* Kb  = (unsigned short*)(ws + 2 * SZ_H + 4 * SZ_W);
  unsigned short* Vb  = (unsigned short*)(ws + 3 * SZ_H + 4 * SZ_W);
  unsigned short* VTb = hb;   // h no longer needed after QKV GEMMs
  unsigned short* Cb  = Vb;   // V no longer needed after transpose

  // converts
  cvt_bf16<<<4096, 256, 0, stream>>>(h, hb, M_ * E_ / 4, 1.0f);
  cvt_bf16<<<1024, 256, 0, stream>>>(Wq, wqb, E_ * E_ / 4, 0.125f);  // fold 1/sqrt(D)
  cvt_bf16<<<1024, 256, 0, stream>>>(Wk, wkb, E_ * E_ / 4, 1.0f);
  cvt_bf16<<<1024, 256, 0, stream>>>(Wv, wvb, E_ * E_ / 4, 1.0f);
  cvt_bf16<<<1024, 256, 0, stream>>>(Wo, wob, E_ * E_ / 4, 1.0f);

  dim3 gg(M_ / 128, E_ / 128);
  gemm_bt<1><<<gg, 256, 0, stream>>>(hb, wqb, Qb, M_, E_, E_);
  gemm_bt<1><<<gg, 256, 0, stream>>>(hb, wkb, Kb, M_, E_, E_);
  gemm_bt<1><<<gg, 256, 0, stream>>>(hb, wvb, Vb, M_, E_, E_);

  transpose_v<<<dim3(S_ / 64, H_, B_), 256, 0, stream>>>(Vb, VTb);

  attn<<<dim3(S_ / 64, B_ * H_), 256, 0, stream>>>(Qb, Kb, VTb, Cb);

  gemm_bt<0><<<gg, 256, 0, stream>>>(Cb, wob, out, M_, E_, E_);
}

// Round 2
// 268.516 us; speedup vs baseline: 1.2993x; 1.2993x over previous
//
#include <hip/hip_runtime.h>

#define B_ 2
#define S_ 2048
#define E_ 1024
#define H_ 16
#define D_ 64
#define M_ (B_*S_)   // 4096

typedef __attribute__((ext_vector_type(8))) short bf16x8;   // 8 bf16 in 4 VGPRs
typedef __attribute__((ext_vector_type(4))) float f32x4;
typedef __attribute__((ext_vector_type(8))) unsigned short u16x8;
typedef __attribute__((ext_vector_type(4))) unsigned short u16x4;

__device__ __forceinline__ unsigned short f2bf(float f) {
  union { float f; unsigned u; } a; a.f = f;
  unsigned u = a.u;
  return (unsigned short)((u + 0x7FFFu + ((u >> 16) & 1u)) >> 16);  // RNE
}

__device__ __forceinline__ void gload_lds16(const void* g, void* l) {
  __builtin_amdgcn_global_load_lds(
      (const __attribute__((address_space(1))) void*)g,
      (__attribute__((address_space(3))) void*)l, 16, 0, 0);
}

// ---------------- fp32 -> bf16 convert (with scale fold) ----------------
__global__ __launch_bounds__(256) void cvt_bf16(const float* __restrict__ src,
                                                unsigned short* __restrict__ dst,
                                                int n4, float scale) {
  int i = blockIdx.x * blockDim.x + threadIdx.x;
  if (i < n4) {
    float4 v = ((const float4*)src)[i];
    u16x4 o;
    o[0] = f2bf(v.x * scale);
    o[1] = f2bf(v.y * scale);
    o[2] = f2bf(v.z * scale);
    o[3] = f2bf(v.w * scale);
    ((u16x4*)dst)[i] = o;
  }
}

// ---------------- GEMM: C[m,n] = sum_k A[m,k] * W[n,k]  (y = x @ W^T) ----
// 128x128 tile, BK=32, 256 threads = 4 waves (2x2), each wave 64x64.
// LDS rows are 64B (16 banks): XOR-swizzle chunk c -> c ^ ((row>>1)&3)
// applied at the GLOBAL source (gload_lds dest must stay linear) and at read.
template<int OUT_BF16>
__global__ __launch_bounds__(256) void gemm_bt(const unsigned short* __restrict__ A,
                                               const unsigned short* __restrict__ W,
                                               void* __restrict__ Cv,
                                               int M, int N, int K) {
  __shared__ unsigned short As[128 * 32];
  __shared__ unsigned short Bs[128 * 32];
  const int tid = threadIdx.x;
  const int lane = tid & 63, wave = tid >> 6;
  const int wr = wave >> 1, wc = wave & 1;
  const int lq = lane & 15, lg = lane >> 4;
  const int row0 = blockIdx.x * 128, col0 = blockIdx.y * 128;
  f32x4 acc[4][4] = {};

  for (int kt = 0; kt < K; kt += 32) {
#pragma unroll
    for (int i = 0; i < 2; ++i) {
      int t = tid + i * 256;
      int rr = t >> 2;
      int sch = (t & 3) ^ ((rr >> 1) & 3);   // pre-swizzled source chunk
      gload_lds16(A + (size_t)(row0 + rr) * K + kt + sch * 8, &As[t * 8]);
      gload_lds16(W + (size_t)(col0 + rr) * K + kt + sch * 8, &Bs[t * 8]);
    }
    __syncthreads();
    bf16x8 af[4], bfr[4];
#pragma unroll
    for (int mi = 0; mi < 4; ++mi) {
      int row = wr * 64 + mi * 16 + lq;
      af[mi] = *(const bf16x8*)&As[row * 32 + (lg ^ ((row >> 1) & 3)) * 8];
    }
#pragma unroll
    for (int ni = 0; ni < 4; ++ni) {
      int row = wc * 64 + ni * 16 + lq;
      bfr[ni] = *(const bf16x8*)&Bs[row * 32 + (lg ^ ((row >> 1) & 3)) * 8];
    }
#pragma unroll
    for (int mi = 0; mi < 4; ++mi)
#pragma unroll
      for (int ni = 0; ni < 4; ++ni)
        acc[mi][ni] = __builtin_amdgcn_mfma_f32_16x16x32_bf16(af[mi], bfr[ni], acc[mi][ni], 0, 0, 0);
    __syncthreads();
  }

#pragma unroll
  for (int mi = 0; mi < 4; ++mi)
#pragma unroll
    for (int ni = 0; ni < 4; ++ni) {
      int row = row0 + wr * 64 + mi * 16 + lg * 4;
      int col = col0 + wc * 64 + ni * 16 + lq;
#pragma unroll
      for (int r = 0; r < 4; ++r) {
        float v = acc[mi][ni][r];
        if (OUT_BF16) ((unsigned short*)Cv)[(size_t)(row + r) * N + col] = f2bf(v);
        else          ((float*)Cv)[(size_t)(row + r) * N + col] = v;
      }
    }
}

// ---------------- V [B,S,E](bf16) -> VT [B*H*D, S](bf16) -----------------
__global__ __launch_bounds__(256) void transpose_v(const unsigned short* __restrict__ V,
                                                   unsigned short* __restrict__ VT) {
  __shared__ unsigned short tile[64][72];
  const int tid = threadIdx.x;
  const int s0 = blockIdx.x * 64;
  const int h = blockIdx.y;
  const int b = blockIdx.z;
  const int r = tid >> 3;
  const int c = (tid & 7) * 8;
  const unsigned short* src = V + ((size_t)(b * S_) + s0) * E_ + h * 64;
#pragma unroll
  for (int i = 0; i < 2; ++i) {
    int rr = r + i * 32;
    u16x8 v = *(const u16x8*)(src + (size_t)rr * E_ + c);
#pragma unroll
    for (int j = 0; j < 8; ++j) tile[rr][c + j] = v[j];
  }
  __syncthreads();
  unsigned short* dst = VT + ((size_t)((b * H_ + h) * 64)) * S_ + s0;
#pragma unroll
  for (int i = 0; i < 2; ++i) {
    int d = r + i * 32;
    u16x8 o;
#pragma unroll
    for (int j = 0; j < 8; ++j) o[j] = tile[c + j][d];
    *(u16x8*)(dst + (size_t)d * S_ + c) = o;
  }
}

// ---------------- flash attention ---------------------------------------
// grid: (S/64, B*H). 256 threads = 4 waves; wave w owns q rows [w*16, w*16+16).
// Score scale 1/8 is folded into W_q. Swapped QK^T: S^T = mfma(K, Q).
// Ks/Vs rows are 128B (32 banks): XOR-swizzle chunk c -> c ^ (row&7),
// pre-swizzled at the global source, swizzled chunk index at read.
// Ps padded to 72 elems/row (144B) -> 2-way residual conflicts (free).
__global__ __launch_bounds__(256) void attn(const unsigned short* __restrict__ Q,
                                            const unsigned short* __restrict__ K,
                                            const unsigned short* __restrict__ VT,
                                            unsigned short* __restrict__ ctx) {
  __shared__ unsigned short Ks[64 * 64];       // [key][d], swizzled
  __shared__ unsigned short Vs[64 * 64];       // [dv][key], swizzled
  __shared__ unsigned short Ps[4][16 * 72];    // per wave: [q][key], padded
  const int tid = threadIdx.x, lane = tid & 63, wave = tid >> 6;
  const int lq = lane & 15, lg = lane >> 4;
  const int bh = blockIdx.y, b = bh >> 4, h = bh & 15;
  const int q0 = blockIdx.x * 64;

  const unsigned short* Qbase = Q + ((size_t)(b * S_) + q0 + wave * 16 + lq) * E_ + h * 64;
  bf16x8 qf0 = *(const bf16x8*)(Qbase + lg * 8);
  bf16x8 qf1 = *(const bf16x8*)(Qbase + 32 + lg * 8);
  const unsigned short* Kbase = K + (size_t)(b * S_) * E_ + h * 64;
  const unsigned short* Vtb = VT + (size_t)((b * H_ + h) * 64) * S_;

  f32x4 oacc[4] = {};
  float m_run = -1e30f, l_run = 0.f;

  for (int kc = 0; kc < S_; kc += 64) {
    __syncthreads();
#pragma unroll
    for (int i = 0; i < 2; ++i) {
      int tt = tid + i * 256;
      int r = tt >> 3;
      int sch = (tt & 7) ^ (r & 7);          // pre-swizzled source chunk
      gload_lds16(Kbase + (size_t)(kc + r) * E_ + sch * 8, &Ks[tt * 8]);
      gload_lds16(Vtb + (size_t)r * S_ + kc + sch * 8, &Vs[tt * 8]);
    }
    __syncthreads();

    // S^T[key][q] for 64 keys
    f32x4 st[4] = {};
#pragma unroll
    for (int mf = 0; mf < 4; ++mf) {
      int row = mf * 16 + lq;
      bf16x8 kf0 = *(const bf16x8*)&Ks[row * 64 + ((lg ^ (row & 7)) * 8)];
      bf16x8 kf1 = *(const bf16x8*)&Ks[row * 64 + (((4 + lg) ^ (row & 7)) * 8)];
      st[mf] = __builtin_amdgcn_mfma_f32_16x16x32_bf16(kf0, qf0, st[mf], 0, 0, 0);
      st[mf] = __builtin_amdgcn_mfma_f32_16x16x32_bf16(kf1, qf1, st[mf], 0, 0, 0);
    }

    // online softmax for q = lq (4 redundant lanes per q)
    float cm = -1e30f;
#pragma unroll
    for (int mf = 0; mf < 4; ++mf)
#pragma unroll
      for (int r = 0; r < 4; ++r) cm = fmaxf(cm, st[mf][r]);
    cm = fmaxf(cm, __shfl_xor(cm, 16));
    cm = fmaxf(cm, __shfl_xor(cm, 32));
    float m_new = fmaxf(m_run, cm);
    float alpha = __expf(m_run - m_new);
    float ls = 0.f;
#pragma unroll
    for (int mf = 0; mf < 4; ++mf) {
      u16x4 pb;
#pragma unroll
      for (int r = 0; r < 4; ++r) {
        float p = __expf(st[mf][r] - m_new);
        ls += p;
        pb[r] = f2bf(p);
      }
      *(u16x4*)&Ps[wave][lq * 72 + mf * 16 + lg * 4] = pb;  // P[q][key]
    }
    ls += __shfl_xor(ls, 16);
    ls += __shfl_xor(ls, 32);
    l_run = l_run * alpha + ls;
    m_run = m_new;
    asm volatile("s_waitcnt lgkmcnt(0)" ::: "memory");

    // rescale O (q = lg*4 + r in PV layout)
#pragma unroll
    for (int r = 0; r < 4; ++r) {
      float ar = __shfl(alpha, lg * 4 + r);
#pragma unroll
      for (int nf = 0; nf < 4; ++nf) oacc[nf][r] *= ar;
    }

    // O[q][dv] += P @ V
#pragma unroll
    for (int ks = 0; ks < 2; ++ks) {
      bf16x8 pf = *(const bf16x8*)&Ps[wave][lq * 72 + ks * 32 + lg * 8];
#pragma unroll
      for (int nf = 0; nf < 4; ++nf) {
        int row = nf * 16 + lq;
        bf16x8 vf = *(const bf16x8*)&Vs[row * 64 + (((ks * 4 + lg) ^ (row & 7)) * 8)];
        oacc[nf] = __builtin_amdgcn_mfma_f32_16x16x32_bf16(pf, vf, oacc[nf], 0, 0, 0);
      }
    }
  }

  // normalize + store ctx (bf16, [B,S,E] layout)
#pragma unroll
  for (int r = 0; r < 4; ++r) {
    float lr = __shfl(l_run, lg * 4 + r);
    float inv = 1.f / lr;
#pragma unroll
    for (int nf = 0; nf < 4; ++nf) {
      ctx[((size_t)(b * S_) + q0 + wave * 16 + lg * 4 + r) * E_ + h * 64 + nf * 16 + lq] =
          f2bf(oacc[nf][r] * inv);
    }
  }
}

// ---------------- launch -------------------------------------------------
extern "C" void kernel_launch(void* const* d_in, const int* in_sizes, int n_in,
                              void* d_out, int out_size, void* d_ws, size_t ws_size,
                              hipStream_t stream) {
  const float* h  = (const float*)d_in[0];
  const float* Wq = (const float*)d_in[1];
  const float* Wk = (const float*)d_in[2];
  const float* Wv = (const float*)d_in[3];
  const float* Wo = (const float*)d_in[4];
  float* out = (float*)d_out;
  char* ws = (char*)d_ws;

  const size_t SZ_H = (size_t)M_ * E_ * 2;   // 8 MiB
  const size_t SZ_W = (size_t)E_ * E_ * 2;   // 2 MiB
  unsigned short* hb  = (unsigned short*)(ws);
  unsigned short* wqb = (unsigned short*)(ws + SZ_H);
  unsigned short* wkb = (unsigned short*)(ws + SZ_H + SZ_W);
  unsigned short* wvb = (unsigned short*)(ws + SZ_H + 2 * SZ_W);
  unsigned short* wob = (unsigned short*)(ws + SZ_H + 3 * SZ_W);
  unsigned short* Qb  = (unsigned short*)(ws + SZ_H + 4 * SZ_W);
  unsigned short* Kb  = (unsigned short*)(ws + 2 * SZ_H + 4 * SZ_W);
  unsigned short* Vb  = (unsigned short*)(ws + 3 * SZ_H + 4 * SZ_W);
  unsigned short* VTb = hb;   // h no longer needed after QKV GEMMs
  unsigned short* Cb  = Vb;   // V no longer needed after transpose

  // converts
  cvt_bf16<<<4096, 256, 0, stream>>>(h, hb, M_ * E_ / 4, 1.0f);
  cvt_bf16<<<1024, 256, 0, stream>>>(Wq, wqb, E_ * E_ / 4, 0.125f);  // fold 1/sqrt(D)
  cvt_bf16<<<1024, 256, 0, stream>>>(Wk, wkb, E_ * E_ / 4, 1.0f);
  cvt_bf16<<<1024, 256, 0, stream>>>(Wv, wvb, E_ * E_ / 4, 1.0f);
  cvt_bf16<<<1024, 256, 0, stream>>>(Wo, wob, E_ * E_ / 4, 1.0f);

  dim3 gg(M_ / 128, E_ / 128);
  gemm_bt<1><<<gg, 256, 0, stream>>>(hb, wqb, Qb, M_, E_, E_);
  gemm_bt<1><<<gg, 256, 0, stream>>>(hb, wkb, Kb, M_, E_, E_);
  gemm_bt<1><<<gg, 256, 0, stream>>>(hb, wvb, Vb, M_, E_, E_);

  transpose_v<<<dim3(S_ / 64, H_, B_), 256, 0, stream>>>(Vb, VTb);

  attn<<<dim3(S_ / 64, B_ * H_), 256, 0, stream>>>(Qb, Kb, VTb, Cb);

  gemm_bt<0><<<gg, 256, 0, stream>>>(Cb, wob, out, M_, E_, E_);
}

// Round 6
// 225.160 us; speedup vs baseline: 1.5495x; 1.1926x over previous
//
#include <hip/hip_runtime.h>

#define B_ 2
#define S_ 2048
#define E_ 1024
#define H_ 16
#define D_ 64
#define M_ (B_*S_)   // 4096

typedef __attribute__((ext_vector_type(8))) short bf16x8;   // 8 bf16 in 4 VGPRs
typedef __attribute__((ext_vector_type(4))) float f32x4;
typedef __attribute__((ext_vector_type(8))) unsigned short u16x8;
typedef __attribute__((ext_vector_type(4))) unsigned short u16x4;

__device__ __forceinline__ unsigned short f2bf(float f) {
  union { float f; unsigned u; } a; a.f = f;
  unsigned u = a.u;
  return (unsigned short)((u + 0x7FFFu + ((u >> 16) & 1u)) >> 16);  // RNE
}

__device__ __forceinline__ void gload_lds16(const void* g, void* l) {
  __builtin_amdgcn_global_load_lds(
      (const __attribute__((address_space(1))) void*)g,
      (__attribute__((address_space(3))) void*)l, 16, 0, 0);
}

// ---------------- fp32 -> bf16 convert (with scale fold) ----------------
__global__ __launch_bounds__(256) void cvt_bf16(const float* __restrict__ src,
                                                unsigned short* __restrict__ dst,
                                                int n4, float scale) {
  int i = blockIdx.x * blockDim.x + threadIdx.x;
  if (i < n4) {
    float4 v = ((const float4*)src)[i];
    u16x4 o;
    o[0] = f2bf(v.x * scale);
    o[1] = f2bf(v.y * scale);
    o[2] = f2bf(v.z * scale);
    o[3] = f2bf(v.w * scale);
    ((u16x4*)dst)[i] = o;
  }
}

// ---------------- GEMM core: C[m,n] = sum_k A[m,k] * W[n,k] -------------
// 128x128 tile, BK=32, 256 threads = 4 waves (2x2), each wave 64x64.
// LDS rows 64B: XOR-swizzle chunk c -> c ^ ((row>>1)&3), pre-swizzled at the
// global source (gload_lds dest stays linear), same swizzle at read.
template<int OUT_BF16>
__device__ __forceinline__ void gemm_body(const unsigned short* __restrict__ A,
                                          const unsigned short* __restrict__ W,
                                          void* __restrict__ Cv,
                                          int row0, int col0, int N, int K,
                                          unsigned short* As, unsigned short* Bs) {
  const int tid = threadIdx.x;
  const int lane = tid & 63, wave = tid >> 6;
  const int wr = wave >> 1, wc = wave & 1;
  const int lq = lane & 15, lg = lane >> 4;
  f32x4 acc[4][4] = {};

  for (int kt = 0; kt < K; kt += 32) {
#pragma unroll
    for (int i = 0; i < 2; ++i) {
      int t = tid + i * 256;
      int rr = t >> 2;
      int sch = (t & 3) ^ ((rr >> 1) & 3);   // pre-swizzled source chunk
      gload_lds16(A + (size_t)(row0 + rr) * K + kt + sch * 8, &As[t * 8]);
      gload_lds16(W + (size_t)(col0 + rr) * K + kt + sch * 8, &Bs[t * 8]);
    }
    __syncthreads();
    bf16x8 af[4], bfr[4];
#pragma unroll
    for (int mi = 0; mi < 4; ++mi) {
      int row = wr * 64 + mi * 16 + lq;
      af[mi] = *(const bf16x8*)&As[row * 32 + (lg ^ ((row >> 1) & 3)) * 8];
    }
#pragma unroll
    for (int ni = 0; ni < 4; ++ni) {
      int row = wc * 64 + ni * 16 + lq;
      bfr[ni] = *(const bf16x8*)&Bs[row * 32 + (lg ^ ((row >> 1) & 3)) * 8];
    }
#pragma unroll
    for (int mi = 0; mi < 4; ++mi)
#pragma unroll
      for (int ni = 0; ni < 4; ++ni)
        acc[mi][ni] = __builtin_amdgcn_mfma_f32_16x16x32_bf16(af[mi], bfr[ni], acc[mi][ni], 0, 0, 0);
    __syncthreads();
  }

#pragma unroll
  for (int mi = 0; mi < 4; ++mi)
#pragma unroll
    for (int ni = 0; ni < 4; ++ni) {
      int row = row0 + wr * 64 + mi * 16 + lg * 4;
      int col = col0 + wc * 64 + ni * 16 + lq;
#pragma unroll
      for (int r = 0; r < 4; ++r) {
        float v = acc[mi][ni][r];
        if (OUT_BF16) ((unsigned short*)Cv)[(size_t)(row + r) * N + col] = f2bf(v);
        else          ((float*)Cv)[(size_t)(row + r) * N + col] = v;
      }
    }
}

// Fused QKV projection: grid (M/128, 3*E/128). blockIdx.y selects matrix.
__global__ __launch_bounds__(256) void gemm_qkv(const unsigned short* __restrict__ A,
                                                const unsigned short* __restrict__ Wq,
                                                const unsigned short* __restrict__ Wk,
                                                const unsigned short* __restrict__ Wv,
                                                unsigned short* __restrict__ Qb,
                                                unsigned short* __restrict__ Kb,
                                                unsigned short* __restrict__ Vb) {
  __shared__ unsigned short As[128 * 32];
  __shared__ unsigned short Bs[128 * 32];
  const int mat = blockIdx.y >> 3;
  const int col0 = (blockIdx.y & 7) * 128;
  const unsigned short* W = (mat == 0) ? Wq : (mat == 1) ? Wk : Wv;
  unsigned short* C = (mat == 0) ? Qb : (mat == 1) ? Kb : Vb;
  gemm_body<1>(A, W, C, blockIdx.x * 128, col0, E_, E_, As, Bs);
}

__global__ __launch_bounds__(256) void gemm_out(const unsigned short* __restrict__ A,
                                                const unsigned short* __restrict__ W,
                                                float* __restrict__ C) {
  __shared__ unsigned short As[128 * 32];
  __shared__ unsigned short Bs[128 * 32];
  gemm_body<0>(A, W, C, blockIdx.x * 128, blockIdx.y * 128, E_, E_, As, Bs);
}

// ---------------- V [B,S,E](bf16) -> VT [B*H*D, S](bf16) -----------------
__global__ __launch_bounds__(256) void transpose_v(const unsigned short* __restrict__ V,
                                                   unsigned short* __restrict__ VT) {
  __shared__ unsigned short tile[64][72];
  const int tid = threadIdx.x;
  const int s0 = blockIdx.x * 64;
  const int h = blockIdx.y;
  const int b = blockIdx.z;
  const int r = tid >> 3;
  const int c = (tid & 7) * 8;
  const unsigned short* src = V + ((size_t)(b * S_) + s0) * E_ + h * 64;
#pragma unroll
  for (int i = 0; i < 2; ++i) {
    int rr = r + i * 32;
    u16x8 v = *(const u16x8*)(src + (size_t)rr * E_ + c);
#pragma unroll
    for (int j = 0; j < 8; ++j) tile[rr][c + j] = v[j];
  }
  __syncthreads();
  unsigned short* dst = VT + ((size_t)((b * H_ + h) * 64)) * S_ + s0;
#pragma unroll
  for (int i = 0; i < 2; ++i) {
    int d = r + i * 32;
    u16x8 o;
#pragma unroll
    for (int j = 0; j < 8; ++j) o[j] = tile[c + j][d];
    *(u16x8*)(dst + (size_t)d * S_ + c) = o;
  }
}

// ---------------- flash attention ---------------------------------------
// grid: (S/64, B*H). 256 threads = 4 waves; wave w owns q rows [w*16, w*16+16).
// Score scale 0.125*log2(e) folded into W_q -> softmax in exp2 domain.
// Swapped QK^T: S^T = mfma(K, Q). Ks/Vs XOR-swizzled (chunk ^ row&7).
// Round 4/5: unconditional rescale (round-2 proven) + f2bf packing (proven).
__global__ __launch_bounds__(256) void attn(const unsigned short* __restrict__ Q,
                                            const unsigned short* __restrict__ K,
                                            const unsigned short* __restrict__ VT,
                                            unsigned short* __restrict__ ctx) {
  __shared__ unsigned short Ks[64 * 64];       // [key][d], swizzled
  __shared__ unsigned short Vs[64 * 64];       // [dv][key], swizzled
  __shared__ unsigned short Ps[4][16 * 72];    // per wave: [q][key], padded
  const int tid = threadIdx.x, lane = tid & 63, wave = tid >> 6;
  const int lq = lane & 15, lg = lane >> 4;
  const int bh = blockIdx.y, b = bh >> 4, h = bh & 15;
  const int q0 = blockIdx.x * 64;

  const unsigned short* Qbase = Q + ((size_t)(b * S_) + q0 + wave * 16 + lq) * E_ + h * 64;
  bf16x8 qf0 = *(const bf16x8*)(Qbase + lg * 8);
  bf16x8 qf1 = *(const bf16x8*)(Qbase + 32 + lg * 8);
  const unsigned short* Kbase = K + (size_t)(b * S_) * E_ + h * 64;
  const unsigned short* Vtb = VT + (size_t)((b * H_ + h) * 64) * S_;

  f32x4 oacc[4] = {};
  float m_run = -1e30f, l_run = 0.f;

  for (int kc = 0; kc < S_; kc += 64) {
    __syncthreads();
#pragma unroll
    for (int i = 0; i < 2; ++i) {
      int tt = tid + i * 256;
      int r = tt >> 3;
      int sch = (tt & 7) ^ (r & 7);          // pre-swizzled source chunk
      gload_lds16(Kbase + (size_t)(kc + r) * E_ + sch * 8, &Ks[tt * 8]);
      gload_lds16(Vtb + (size_t)r * S_ + kc + sch * 8, &Vs[tt * 8]);
    }
    __syncthreads();

    // S^T[key][q] for 64 keys (log2-domain scores)
    f32x4 st[4] = {};
#pragma unroll
    for (int mf = 0; mf < 4; ++mf) {
      int row = mf * 16 + lq;
      bf16x8 kf0 = *(const bf16x8*)&Ks[row * 64 + ((lg ^ (row & 7)) * 8)];
      bf16x8 kf1 = *(const bf16x8*)&Ks[row * 64 + (((4 + lg) ^ (row & 7)) * 8)];
      st[mf] = __builtin_amdgcn_mfma_f32_16x16x32_bf16(kf0, qf0, st[mf], 0, 0, 0);
      st[mf] = __builtin_amdgcn_mfma_f32_16x16x32_bf16(kf1, qf1, st[mf], 0, 0, 0);
    }

    // tile max over 64 keys for q = lq (tree; 4 redundant lanes per q)
    float c0 = fmaxf(fmaxf(st[0][0], st[0][1]), fmaxf(st[0][2], st[0][3]));
    float c1 = fmaxf(fmaxf(st[1][0], st[1][1]), fmaxf(st[1][2], st[1][3]));
    float c2 = fmaxf(fmaxf(st[2][0], st[2][1]), fmaxf(st[2][2], st[2][3]));
    float c3 = fmaxf(fmaxf(st[3][0], st[3][1]), fmaxf(st[3][2], st[3][3]));
    float cm = fmaxf(fmaxf(c0, c1), fmaxf(c2, c3));
    cm = fmaxf(cm, __shfl_xor(cm, 16));
    cm = fmaxf(cm, __shfl_xor(cm, 32));

    float m_new = fmaxf(m_run, cm);
    float alpha = __builtin_amdgcn_exp2f(m_run - m_new);

    float ls = 0.f;
#pragma unroll
    for (int mf = 0; mf < 4; ++mf) {
      u16x4 pb;
#pragma unroll
      for (int r = 0; r < 4; ++r) {
        float p = __builtin_amdgcn_exp2f(st[mf][r] - m_new);
        ls += p;
        pb[r] = f2bf(p);
      }
      *(u16x4*)&Ps[wave][lq * 72 + mf * 16 + lg * 4] = pb;  // P[q][key]
    }
    ls += __shfl_xor(ls, 16);
    ls += __shfl_xor(ls, 32);
    l_run = l_run * alpha + ls;
    m_run = m_new;
    asm volatile("s_waitcnt lgkmcnt(0)" ::: "memory");

    // rescale O (q = lg*4 + r in PV layout)
#pragma unroll
    for (int r = 0; r < 4; ++r) {
      float ar = __shfl(alpha, lg * 4 + r);
#pragma unroll
      for (int nf = 0; nf < 4; ++nf) oacc[nf][r] *= ar;
    }

    // O[q][dv] += P @ V
#pragma unroll
    for (int ks = 0; ks < 2; ++ks) {
      bf16x8 pf = *(const bf16x8*)&Ps[wave][lq * 72 + ks * 32 + lg * 8];
#pragma unroll
      for (int nf = 0; nf < 4; ++nf) {
        int row = nf * 16 + lq;
        bf16x8 vf = *(const bf16x8*)&Vs[row * 64 + (((ks * 4 + lg) ^ (row & 7)) * 8)];
        oacc[nf] = __builtin_amdgcn_mfma_f32_16x16x32_bf16(pf, vf, oacc[nf], 0, 0, 0);
      }
    }
  }

  // normalize + store ctx (bf16, [B,S,E] layout)
#pragma unroll
  for (int r = 0; r < 4; ++r) {
    float lr = __shfl(l_run, lg * 4 + r);
    float inv = 1.f / lr;
#pragma unroll
    for (int nf = 0; nf < 4; ++nf) {
      ctx[((size_t)(b * S_) + q0 + wave * 16 + lg * 4 + r) * E_ + h * 64 + nf * 16 + lq] =
          f2bf(oacc[nf][r] * inv);
    }
  }
}

// ---------------- launch -------------------------------------------------
extern "C" void kernel_launch(void* const* d_in, const int* in_sizes, int n_in,
                              void* d_out, int out_size, void* d_ws, size_t ws_size,
                              hipStream_t stream) {
  const float* h  = (const float*)d_in[0];
  const float* Wq = (const float*)d_in[1];
  const float* Wk = (const float*)d_in[2];
  const float* Wv = (const float*)d_in[3];
  const float* Wo = (const float*)d_in[4];
  float* out = (float*)d_out;
  char* ws = (char*)d_ws;

  const size_t SZ_H = (size_t)M_ * E_ * 2;   // 8 MiB
  const size_t SZ_W = (size_t)E_ * E_ * 2;   // 2 MiB
  unsigned short* hb  = (unsigned short*)(ws);
  unsigned short* wqb = (unsigned short*)(ws + SZ_H);
  unsigned short* wkb = (unsigned short*)(ws + SZ_H + SZ_W);
  unsigned short* wvb = (unsigned short*)(ws + SZ_H + 2 * SZ_W);
  unsigned short* wob = (unsigned short*)(ws + SZ_H + 3 * SZ_W);
  unsigned short* Qb  = (unsigned short*)(ws + SZ_H + 4 * SZ_W);
  unsigned short* Kb  = (unsigned short*)(ws + 2 * SZ_H + 4 * SZ_W);
  unsigned short* Vb  = (unsigned short*)(ws + 3 * SZ_H + 4 * SZ_W);
  unsigned short* VTb = hb;   // h no longer needed after QKV GEMMs
  unsigned short* Cb  = Vb;   // V no longer needed after transpose

  // converts; fold score-scale * log2(e) into W_q (softmax in exp2 domain)
  const float QSCALE = 0.125f * 1.44269504f;
  cvt_bf16<<<4096, 256, 0, stream>>>(h, hb, M_ * E_ / 4, 1.0f);
  cvt_bf16<<<1024, 256, 0, stream>>>(Wq, wqb, E_ * E_ / 4, QSCALE);
  cvt_bf16<<<1024, 256, 0, stream>>>(Wk, wkb, E_ * E_ / 4, 1.0f);
  cvt_bf16<<<1024, 256, 0, stream>>>(Wv, wvb, E_ * E_ / 4, 1.0f);
  cvt_bf16<<<1024, 256, 0, stream>>>(Wo, wob, E_ * E_ / 4, 1.0f);

  // fused QKV projection: 3 blocks/CU instead of 1
  gemm_qkv<<<dim3(M_ / 128, 3 * E_ / 128), 256, 0, stream>>>(hb, wqb, wkb, wvb, Qb, Kb, Vb);

  transpose_v<<<dim3(S_ / 64, H_, B_), 256, 0, stream>>>(Vb, VTb);

  attn<<<dim3(S_ / 64, B_ * H_), 256, 0, stream>>>(Qb, Kb, VTb, Cb);

  gemm_out<<<dim3(M_ / 128, E_ / 128), 256, 0, stream>>>(Cb, wob, out);
}